// Round 3
// baseline (30.931 us; speedup 1.0000x reference)
//
#include <hip/hip_runtime.h>
#include <math.h>

#define TB 2048
#define TK 128
#define TD 512

// ---------------------------------------------------------------------------
// Fused dist kernel: computes per-class params (rsqrt/scale) into LDS on the
// fly, accumulates partial Mahalanobis dist_sq over a d-slice, and (rb==0
// blocks only) the partial log-determinant for the slice.
//
// 256 threads = 32 k-groups (4 k each) x 8 row-groups (8 rows each) = 64 rows.
// x is read directly from global (32 lanes broadcast same address -> L1),
// keeping the LDS pipe for params only.
// ---------------------------------------------------------------------------
template<int DSPLIT>
__global__ __launch_bounds__(256, 2) void dist_fused(
        const float* __restrict__ x, const float* __restrict__ C,
        const float* __restrict__ Dm, float* part, float* logdet_part) {
    constexpr int DLEN = TD / DSPLIT;
    constexpr int DC = (DLEN < 64) ? DLEN : 64;
    constexpr int NCH = DLEN / DC;
    constexpr int R = 8;
    constexpr int BROWS = 64;

    __shared__ float sa[DC][TK];   // u = rsqrt(|D|+eps), layout [d][k]
    __shared__ float sb[DC][TK];   // c*u

    const int tid = threadIdx.x;
    const int rb = blockIdx.x / DSPLIT;
    const int ds = blockIdx.x % DSPLIT;
    const int b0 = rb * BROWS;
    const int dstart = ds * DLEN;

    // staging mapping: each pair of threads covers one k-row's DC-wide slice
    const int kk = tid >> 1;                   // 0..127
    const int dhalf = (tid & 1) * (DC / 2);    // 0 or DC/2

    // compute mapping
    const int kg = tid & 31;
    const int k0 = kg * 4;
    const int rowbase = (tid >> 5) * R;
    const float* xrow = x + (size_t)(b0 + rowbase) * TD + dstart;

    float acc[R][4];
    #pragma unroll
    for (int r = 0; r < R; ++r)
        #pragma unroll
        for (int j = 0; j < 4; ++j) acc[r][j] = 0.f;

    float lsum = 0.f;

    for (int c = 0; c < NCH; ++c) {
        if (c) __syncthreads();  // WAR on sa/sb
        const int dc0 = dstart + c * DC;
        const float4* Dg = reinterpret_cast<const float4*>(Dm + (size_t)kk * TD + dc0 + dhalf);
        const float4* Cg = reinterpret_cast<const float4*>(C  + (size_t)kk * TD + dc0 + dhalf);
        #pragma unroll
        for (int j = 0; j < DC / 8; ++j) {
            float4 dv = Dg[j];
            float4 cv = Cg[j];
            int db = dhalf + j * 4;
            float da, u;
            da = fabsf(dv.x) + 1e-8f; u = rsqrtf(da); sa[db+0][kk] = u; sb[db+0][kk] = cv.x * u;
            if (rb == 0) lsum += logf(da);
            da = fabsf(dv.y) + 1e-8f; u = rsqrtf(da); sa[db+1][kk] = u; sb[db+1][kk] = cv.y * u;
            if (rb == 0) lsum += logf(da);
            da = fabsf(dv.z) + 1e-8f; u = rsqrtf(da); sa[db+2][kk] = u; sb[db+2][kk] = cv.z * u;
            if (rb == 0) lsum += logf(da);
            da = fabsf(dv.w) + 1e-8f; u = rsqrtf(da); sa[db+3][kk] = u; sb[db+3][kk] = cv.w * u;
            if (rb == 0) lsum += logf(da);
        }
        __syncthreads();

        const float* xc = xrow + c * DC;
        #pragma unroll
        for (int d4 = 0; d4 < DC; d4 += 4) {
            float4 xv[R];
            #pragma unroll
            for (int r = 0; r < R; ++r)
                xv[r] = *reinterpret_cast<const float4*>(&xc[(size_t)r * TD + d4]);
            #pragma unroll
            for (int dd = 0; dd < 4; ++dd) {
                float4 a4 = *reinterpret_cast<const float4*>(&sa[d4 + dd][k0]);
                float4 b4 = *reinterpret_cast<const float4*>(&sb[d4 + dd][k0]);
                #pragma unroll
                for (int r = 0; r < R; ++r) {
                    float xvr = (&xv[r].x)[dd];
                    float t;
                    t = fmaf(xvr, a4.x, -b4.x); acc[r][0] = fmaf(t, t, acc[r][0]);
                    t = fmaf(xvr, a4.y, -b4.y); acc[r][1] = fmaf(t, t, acc[r][1]);
                    t = fmaf(xvr, a4.z, -b4.z); acc[r][2] = fmaf(t, t, acc[r][2]);
                    t = fmaf(xvr, a4.w, -b4.w); acc[r][3] = fmaf(t, t, acc[r][3]);
                }
            }
        }
    }

    #pragma unroll
    for (int r = 0; r < R; ++r) {
        float4 v = make_float4(acc[r][0], acc[r][1], acc[r][2], acc[r][3]);
        *reinterpret_cast<float4*>(
            &part[((size_t)ds * TB + b0 + rowbase + r) * TK + k0]) = v;
    }

    if (rb == 0) {
        // det partial for this d-slice: -0.5 * sum log(|D|+eps)
        lsum += __shfl_xor(lsum, 1, 64);
        if ((tid & 1) == 0) logdet_part[ds * TK + kk] = -0.5f * lsum;
    }
}

// ---------------------------------------------------------------------------
// Epilogue: combine partials + det partials, log-softmax over k, argmax+dist.
// 4 waves/block, 1 row per wave, lane handles k = 2*lane, 2*lane+1.
// NOTE: no __restrict__ on part — may alias out when dsplit==1.
// ---------------------------------------------------------------------------
__global__ __launch_bounds__(256) void finish_kernel(const float* part,
        const float* logdet_part, float* out, int dsplit) {
    const int lane = threadIdx.x & 63;
    const int wv = threadIdx.x >> 6;
    const int b = blockIdx.x * 4 + wv;
    const int k0 = lane * 2;

    float d0 = 0.f, d1 = 0.f;
    for (int s = 0; s < dsplit; ++s) {
        float2 p = *reinterpret_cast<const float2*>(
            &part[((size_t)s * TB + b) * TK + k0]);
        d0 += p.x; d1 += p.y;
    }
    float det0 = 0.f, det1 = 0.f;
    for (int s = 0; s < dsplit; ++s) {
        det0 += logdet_part[s * TK + k0];
        det1 += logdet_part[s * TK + k0 + 1];
    }
    float s0 = fmaf(-0.5f, d0, det0);
    float s1 = fmaf(-0.5f, d1, det1);

    float m = fmaxf(s0, s1);
    #pragma unroll
    for (int msk = 32; msk >= 1; msk >>= 1) m = fmaxf(m, __shfl_xor(m, msk, 64));
    float p0 = expf(s0 - m), p1 = expf(s1 - m);
    float ps = p0 + p1;
    #pragma unroll
    for (int msk = 32; msk >= 1; msk >>= 1) ps += __shfl_xor(ps, msk, 64);
    float lse = logf(ps) + m;

    const float LOGC = -18.420680743952367f;  // ln(1e-8)
    float2 o;
    o.x = fmaxf(s0 - lse, LOGC);
    o.y = fmaxf(s1 - lse, LOGC);
    *reinterpret_cast<float2*>(&out[(size_t)b * TK + k0]) = o;

    // Argmax over s (first index wins ties), carrying dist_sq.
    float bv; int bi; float bd;
    if (s1 > s0) { bv = s1; bi = k0 + 1; bd = d1; }
    else         { bv = s0; bi = k0;     bd = d0; }
    #pragma unroll
    for (int msk = 32; msk >= 1; msk >>= 1) {
        float ov = __shfl_xor(bv, msk, 64);
        int   oi = __shfl_xor(bi, msk, 64);
        float od = __shfl_xor(bd, msk, 64);
        if (ov > bv || (ov == bv && oi < bi)) { bv = ov; bi = oi; bd = od; }
    }
    if (lane == 0) out[(size_t)TB * TK + b] = sqrtf(bd);
}

// ---------------------------------------------------------------------------
extern "C" void kernel_launch(void* const* d_in, const int* in_sizes, int n_in,
                              void* d_out, int out_size, void* d_ws, size_t ws_size,
                              hipStream_t stream) {
    const float* x  = (const float*)d_in[0];
    const float* C  = (const float*)d_in[1];
    const float* Dm = (const float*)d_in[2];
    float* out = (float*)d_out;

    const size_t MB = 1ull << 20;  // TB*TK*4 == 1 MB per split slice

    int dsplit;
    if      (ws_size >= 17 * MB) dsplit = 16;
    else if (ws_size >= 9 * MB)  dsplit = 8;
    else if (ws_size >= 5 * MB)  dsplit = 4;
    else                         dsplit = 1;

    float* part;
    float* logdet_part;
    if (dsplit == 1) {
        part = out;                 // dist_sq staged in resp region, finished in place
        logdet_part = (float*)d_ws; // 512 B
    } else {
        part = (float*)d_ws;
        logdet_part = (float*)((char*)d_ws + (size_t)dsplit * MB);
    }

    switch (dsplit) {
        case 16: dist_fused<16><<<(TB / 64) * 16, 256, 0, stream>>>(x, C, Dm, part, logdet_part); break;
        case 8:  dist_fused<8><<<(TB / 64) * 8, 256, 0, stream>>>(x, C, Dm, part, logdet_part); break;
        case 4:  dist_fused<4><<<(TB / 64) * 4, 256, 0, stream>>>(x, C, Dm, part, logdet_part); break;
        default: dist_fused<1><<<(TB / 64) * 1, 256, 0, stream>>>(x, C, Dm, part, logdet_part); break;
    }

    finish_kernel<<<TB / 4, 256, 0, stream>>>(part, logdet_part, out, dsplit);
}